// Round 8
// baseline (90.738 us; speedup 1.0000x reference)
//
#include <hip/hip_runtime.h>
#include <hip/hip_bf16.h>

// Problem constants
#define BB 2048
#define NN 100
#define INF_ 64
#define HH 256
#define CC 3

typedef __attribute__((ext_vector_type(8))) short s8v;   // 8 bf16 (4 VGPRs)
typedef __attribute__((ext_vector_type(4))) float f4v;   // 4 fp32 acc

static __device__ __forceinline__ unsigned short f2bf(float f) {
    union { float f; unsigned int u; } c; c.f = f;
    unsigned int r = c.u + 0x7FFF + ((c.u >> 16) & 1);   // RNE (host-side precompute path)
    return (unsigned short)(r >> 16);
}
// fast pack: round-half-away (0.5 ulp, same bound as RNE): 2 add + 1 perm
static __device__ __forceinline__ unsigned int pk2rn(float lo, float hi) {
    union { float f; unsigned int u; } a, b;
    a.f = lo; b.f = hi;
    return __builtin_amdgcn_perm(b.u + 0x8000u, a.u + 0x8000u, 0x07060302u);
}
static __device__ __forceinline__ float u2f_lo(unsigned int u) {
    union { float f; unsigned int i; } c; c.i = u << 16; return c.f;
}
static __device__ __forceinline__ float u2f_hi(unsigned int u) {
    union { float f; unsigned int i; } c; c.i = u & 0xffff0000u; return c.f;
}

// ---------------------------------------------------------------------------
// Kernel P: Wcomb[z][64][256] = W_exp @ W_{l,r}[2] (f32)
//           cadd[z][100][256] = (b_exp + pe[n]) @ W_{l,r}[2] + b_{l,r}[2] (f32)
// ---------------------------------------------------------------------------
__global__ __launch_bounds__(256) void precompute_k(
    const float* __restrict__ W_exp, const float* __restrict__ b_exp,
    const float* __restrict__ W_l, const float* __restrict__ b_l,
    const float* __restrict__ W_r, const float* __restrict__ b_r,
    float* __restrict__ Wcomb, float* __restrict__ cadd)
{
    int r = blockIdx.x;           // 0..163
    int z = blockIdx.y;           // 0 = l, 1 = r
    int t = threadIdx.x;          // output col
    const float* Wg = (z ? W_r : W_l) + 2 * HH * HH;  // layer 2
    const float* bg = (z ? b_r : b_l) + 2 * HH;

    __shared__ float sa[HH];
    float a;
    if (r < INF_) {
        a = W_exp[r * HH + t];
    } else {
        int n = r - INF_;
        float div = expf((float)(t & 254) * (-0.03597789207803f));
        float ang = (float)n * div;
        a = b_exp[t] + ((t & 1) ? cosf(ang) : sinf(ang));
    }
    sa[t] = a;
    __syncthreads();

    float acc = 0.f;
    #pragma unroll 8
    for (int h = 0; h < HH; ++h)
        acc += sa[h] * Wg[h * HH + t];

    if (r < INF_) Wcomb[(z * INF_ + r) * HH + t] = acc;
    else          cadd[(z * NN + (r - INF_)) * HH + t] = acc + bg[t];
}

// ---------------------------------------------------------------------------
// Kernel R: rearrange into MFMA fragment layouts.
//  WF (bf16) [z][nt:16][ks:2][lane:64][j:8] : Wcomb[z][k][n],
//      k = ks*32 + 4*(lane>>4) + (j&3) + 16*(j>>2),  n = nt*16 + (lane&15)
//  CFf (f32) [z][mt:7][nt:16][lane:64][r:4] : cadd[z][node][feat],
//      node = mt*16 + (lane&15), feat = nt*16 + (lane>>4)*4 + r  (node>=100 -> 0)
//  (CFf matches the SWAPPED-operand D layout: D[feat][node], col=lane&15=node)
// ---------------------------------------------------------------------------
#define N_WF 32768
#define N_CF4 14336   // float4 slots

__global__ __launch_bounds__(256) void rearrange_k(
    const float* __restrict__ Wcomb, const float* __restrict__ cadd,
    unsigned short* __restrict__ WF, float* __restrict__ CFf)
{
    int i = blockIdx.x * 256 + threadIdx.x;
    if (i < N_WF) {
        int j = i & 7, lane = (i >> 3) & 63, ks = (i >> 9) & 1;
        int nt = (i >> 10) & 15, z = (i >> 14) & 1;
        int k = ks * 32 + 4 * (lane >> 4) + (j & 3) + 16 * (j >> 2);
        int n = nt * 16 + (lane & 15);
        WF[i] = f2bf(Wcomb[(z * INF_ + k) * HH + n]);
    } else if (i < N_WF + N_CF4) {
        int i2 = i - N_WF;
        int lane = i2 & 63, nt = (i2 >> 6) & 15;
        int zm = i2 >> 10;                 // 0..13
        int mt = zm % 7, z = zm / 7;
        int node = mt * 16 + (lane & 15);
        int feat = nt * 16 + (lane >> 4) * 4;
        float4 v = {0.f, 0.f, 0.f, 0.f};
        if (node < NN)
            v = *(const float4*)&cadd[(z * NN + node) * HH + feat];
        *(float4*)&CFf[(size_t)i2 * 4] = v;
    }
}

// ---------------------------------------------------------------------------
// Kernel F (fused): one block per batch, 512 threads (8 waves).
//  Stage x[b] -> LDS bf16 fragments (sxs). Quarter loop (64 cols): swapped
//  MFMA (D[feat][node], CFf C-init) -> perm-pack bf16 -> quarter-local
//  sxl/sxr; balanced edge-logit accumulation (register accumulators).
//  Tail: 8-lane shfl reduce -> lg, softmax -> wv, pooled computed
//  ALGEBRAICALLY: pooled = (wv@x)@Wcomb_l + wv@cadd_l (exact f32), FC.
//  LDS = 12800+12800+14336+1024 = 40960 B = 160KB/4.
// ---------------------------------------------------------------------------
__global__ __launch_bounds__(512, 4) void fused_k(
    const float* __restrict__ x,
    const unsigned short* __restrict__ WF, const float* __restrict__ CFf,
    const float* __restrict__ Wcomb, const float* __restrict__ cadd,
    const float* __restrict__ att, const float* __restrict__ bias,
    const float* __restrict__ Wfc, const float* __restrict__ bfc,
    float* __restrict__ out)
{
    __shared__ unsigned short sxl[NN * 64];    // 12800 B quarter xl (swizzled)
    __shared__ unsigned short sxr[NN * 64];    // 12800 B quarter xr (swizzled)
    __shared__ unsigned short sxs[896 * 8];    // 14336 B x-frags; later lg/wv/ypart
    __shared__ float satt[HH];                 // 1024 B

    int b = blockIdx.x, t = threadIdx.x;
    int wave = t >> 6, lane = t & 63, g = lane >> 4, li = lane & 15;

    if (t < HH) satt[t] = att[2 * HH + t];

    // ---- stage x[b] as bf16 fragments (B-operand for swapped mfma) ----
    const float* xb = x + (size_t)b * (NN * INF_);
    for (int s = t; s < 896; s += 512) {
        int sl = s & 63, ks = (s >> 6) & 1, mt = s >> 7;
        int m = mt * 16 + (sl & 15), gg = sl >> 4;
        union { s8v v; unsigned int u[4]; } a;
        if (m < NN) {
            float4 u = *(const float4*)&xb[m * INF_ + ks * 32 + 4 * gg];
            float4 v = *(const float4*)&xb[m * INF_ + ks * 32 + 16 + 4 * gg];
            a.u[0] = pk2rn(u.x, u.y);
            a.u[1] = pk2rn(u.z, u.w);
            a.u[2] = pk2rn(v.x, v.y);
            a.u[3] = pk2rn(v.z, v.w);
        } else {
            a.u[0] = a.u[1] = a.u[2] = a.u[3] = 0u;
        }
        *(s8v*)&sxs[s * 8] = a.v;
    }

    // ---- per-thread edge slots: edges e = (t>>3)+64i, col chunk c8 = (t&7)*8 ----
    int q8 = t >> 3, c8 = (t & 7) * 8;
    int eBL[5], eBR[5];
    bool eva[5];
    float pv[5], pa[5];
    #pragma unroll
    for (int i = 0; i < 5; ++i) {
        int e = q8 + 64 * i;
        bool inr = (e < 300);
        int es = inr ? (e / 3) : 0;
        int ed = es + (e - 3 * es) - 1;          // dst
        bool v = inr && ed >= 0 && ed < NN;
        eva[i] = v;
        int dd = v ? ed : 0;
        eBL[i] = 2 * (es * 64 + (c8 ^ ((es & 7) << 3)));   // byte, quarter-local
        eBR[i] = 2 * (dd * 64 + (c8 ^ ((dd & 7) << 3)));   // byte, quarter-local
        pv[i] = 0.f; pa[i] = 0.f;
    }

    int z = wave >> 2;          // waves 0-3: xl, 4-7: xr
    int ntw = wave & 3;
    __syncthreads();

    #pragma unroll
    for (int q = 0; q < 4; ++q) {
        // ---- MFMA quarter: wave owns tile (z, nt) ----
        int nt = q * 4 + ntw;
        const s8v* bp = (const s8v*)WF + (size_t)(z * 16 + nt) * 2 * 64;
        s8v w0 = bp[lane];            // ks=0 (A-operand: W^T)
        s8v w1 = bp[64 + lane];       // ks=1
        const s8v* sp = (const s8v*)sxs;
        unsigned short* dstp = z ? sxr : sxl;
        int colbase = ntw * 16 + g * 4;
        #pragma unroll
        for (int mt = 0; mt < 7; ++mt) {
            f4v c = *(const f4v*)&CFf[((size_t)((z * 7 + mt) * 16 + nt) * 64 + lane) * 4];
            s8v a0 = sp[mt * 128 + lane];
            s8v a1 = sp[mt * 128 + 64 + lane];
            c = __builtin_amdgcn_mfma_f32_16x16x32_bf16(w0, a0, c, 0, 0, 0);
            c = __builtin_amdgcn_mfma_f32_16x16x32_bf16(w1, a1, c, 0, 0, 0);
            int node = mt * 16 + li;
            if (mt < 6 || li < 4) {              // node < 100
                unsigned int lo = pk2rn(c[0], c[1]);
                unsigned int hi = pk2rn(c[2], c[3]);
                int elem = node * 64 + (colbase ^ ((li & 7) << 3));
                uint2 wv2 = { lo, hi };
                *(uint2*)&dstp[elem] = wv2;      // ds_write_b64, 4 features
            }
        }
        __syncthreads();

        // ---- balanced logits over this quarter's 64 cols ----
        float4 at0 = *(const float4*)&satt[q * 64 + c8];
        float4 at1 = *(const float4*)&satt[q * 64 + c8 + 4];
        #pragma unroll
        for (int i = 0; i < 5; ++i) {
            if (eva[i]) {
                uint4 ua = *(const uint4*)((const char*)sxl + eBL[i]);
                uint4 ub = *(const uint4*)((const char*)sxr + eBR[i]);
                float fv, fa;
                #define PROC(UL, UR, A0, A1) { \
                    float v0 = u2f_lo(UL) + u2f_lo(UR); \
                    float v1 = u2f_hi(UL) + u2f_hi(UR); \
                    fv = fmaf(A0, v0, fv); fa = fmaf(A0, fabsf(v0), fa); \
                    fv = fmaf(A1, v1, fv); fa = fmaf(A1, fabsf(v1), fa); }
                fv = 0.f; fa = 0.f;
                PROC(ua.x, ub.x, at0.x, at0.y);
                PROC(ua.y, ub.y, at0.z, at0.w);
                PROC(ua.z, ub.z, at1.x, at1.y);
                PROC(ua.w, ub.w, at1.z, at1.w);
                #undef PROC
                pv[i] += fv; pa[i] += fa;
            }
        }
        __syncthreads();
    }

    // sxs frags are dead; carve scratch from it (all 16B-aligned offsets)
    float* lg      = (float*)sxs;          // 300 floats
    float* wvp     = lg + 304;             // 100 floats
    float* partial = wvp + 104;            // 12 floats
    float* ypart   = partial + 16;         // 8*64 floats

    // ---- reduce slot partials across 8-lane groups -> lg ----
    #pragma unroll
    for (int i = 0; i < 5; ++i) {
        // leaky(v) = 0.6v + 0.4|v|, factored: lg = 0.6*pv + 0.4*pa
        float s = fmaf(0.6f, pv[i], 0.4f * pa[i]);
        s += __shfl_xor(s, 1, 64);
        s += __shfl_xor(s, 2, 64);
        s += __shfl_xor(s, 4, 64);
        int e = q8 + 64 * i;
        if ((t & 7) == 0 && e < 300)
            lg[e] = eva[i] ? s : -1e30f;
    }
    __syncthreads();

    // ---- wv[i] = sum over dst j in {i-1,i,i+1} of alpha(i->j) ----
    if (t < NN) {
        int i = t;
        float w = 0.f;
        #pragma unroll
        for (int dj = -1; dj <= 1; ++dj) {
            int j = i + dj;
            if (j < 0 || j >= NN) continue;
            float l0 = (j - 1 >= 0) ? lg[3 * (j - 1) + 2] : -1e30f;  // j-1 -> j
            float l1 = lg[3 * j + 1];                                 // j   -> j
            float l2 = (j + 1 < NN) ? lg[3 * (j + 1) + 0] : -1e30f;  // j+1 -> j
            float mx = fmaxf(fmaxf(l0, l1), l2);
            float den = expf(l0 - mx) + expf(l1 - mx) + expf(l2 - mx);
            float myl = lg[3 * i + dj + 1];
            w += expf(myl - mx) / den;
        }
        wvp[i] = w;
    }
    __syncthreads();

    // ---- y[k] = sum_i wv[i] * x[b][i][k]  (k < 64), per-wave row chunks ----
    {
        int r0 = wave * 13;
        int r1 = (r0 + 13 < NN) ? r0 + 13 : NN;
        float acc = 0.f;
        for (int i = r0; i < r1; ++i)
            acc = fmaf(wvp[i], xb[i * INF_ + lane], acc);
        ypart[wave * 64 + lane] = acc;
    }
    __syncthreads();
    if (t < 64) {
        float s = 0.f;
        #pragma unroll
        for (int w = 0; w < 8; ++w) s += ypart[w * 64 + t];
        ypart[t] = s;                       // y[k]
    }
    __syncthreads();

    // ---- pooled[f] = y @ Wcomb_l[:,f] + wv @ cadd_l[:,f] + 100*bias[f]; FC ----
    if (t < HH) {
        float p = 100.f * bias[2 * HH + t];
        #pragma unroll
        for (int k = 0; k < INF_; k += 4) {
            float4 y4 = *(const float4*)&ypart[k];
            p = fmaf(y4.x, Wcomb[(k + 0) * HH + t], p);
            p = fmaf(y4.y, Wcomb[(k + 1) * HH + t], p);
            p = fmaf(y4.z, Wcomb[(k + 2) * HH + t], p);
            p = fmaf(y4.w, Wcomb[(k + 3) * HH + t], p);
        }
        #pragma unroll
        for (int i = 0; i < NN; i += 4) {
            float4 w4 = *(const float4*)&wvp[i];
            p = fmaf(w4.x, cadd[(i + 0) * HH + t], p);
            p = fmaf(w4.y, cadd[(i + 1) * HH + t], p);
            p = fmaf(w4.z, cadd[(i + 2) * HH + t], p);
            p = fmaf(w4.w, cadd[(i + 3) * HH + t], p);
        }

        float p0 = p * Wfc[t * 3 + 0];
        float p1 = p * Wfc[t * 3 + 1];
        float p2 = p * Wfc[t * 3 + 2];
        #pragma unroll
        for (int off = 32; off; off >>= 1) {
            p0 += __shfl_down(p0, off, 64);
            p1 += __shfl_down(p1, off, 64);
            p2 += __shfl_down(p2, off, 64);
        }
        if (lane == 0) {
            partial[wave * 3 + 0] = p0;
            partial[wave * 3 + 1] = p1;
            partial[wave * 3 + 2] = p2;
        }
    }
    __syncthreads();
    if (t < CC) {
        out[(size_t)b * CC + t] =
            partial[0 * 3 + t] + partial[1 * 3 + t] +
            partial[2 * 3 + t] + partial[3 * 3 + t] + bfc[t];
    }
}

// ---------------------------------------------------------------------------
extern "C" void kernel_launch(void* const* d_in, const int* in_sizes, int n_in,
                              void* d_out, int out_size, void* d_ws, size_t ws_size,
                              hipStream_t stream) {
    const float* x     = (const float*)d_in[0];
    const float* W_exp = (const float*)d_in[1];
    const float* b_exp = (const float*)d_in[2];
    const float* W_l   = (const float*)d_in[3];
    const float* b_l   = (const float*)d_in[4];
    const float* W_r   = (const float*)d_in[5];
    const float* b_r   = (const float*)d_in[6];
    const float* att   = (const float*)d_in[7];
    const float* bias  = (const float*)d_in[8];
    const float* W_fc  = (const float*)d_in[9];
    const float* b_fc  = (const float*)d_in[10];
    float* out = (float*)d_out;

    // workspace layout (16B aligned)
    char* ws = (char*)d_ws;
    float* Wcomb = (float*)ws;                                             // 131072 B
    float* cadd  = (float*)(ws + 131072);                                  // 204800 B
    unsigned short* WF = (unsigned short*)(ws + 131072 + 204800);          // 65536 B
    float* CFf = (float*)(ws + 131072 + 204800 + 65536);                   // 229376 B

    precompute_k<<<dim3(164, 2), 256, 0, stream>>>(W_exp, b_exp, W_l, b_l, W_r, b_r,
                                                   Wcomb, cadd);
    rearrange_k<<<184, 256, 0, stream>>>(Wcomb, cadd, WF, CFf);
    fused_k<<<BB, 512, 0, stream>>>(x, WF, CFf, Wcomb, cadd, att, bias, W_fc, b_fc, out);
}

// Round 9
// 84.637 us; speedup vs baseline: 1.0721x; 1.0721x over previous
//
#include <hip/hip_runtime.h>
#include <hip/hip_bf16.h>

// Problem constants
#define BB 2048
#define NN 100
#define INF_ 64
#define HH 256
#define CC 3
#define QP 72   // padded quarter-row stride (bf16 elems): 144B -> 4-bank rotate/row

typedef __attribute__((ext_vector_type(8))) short s8v;   // 8 bf16 (4 VGPRs)
typedef __attribute__((ext_vector_type(4))) float f4v;   // 4 fp32 acc

static __device__ __forceinline__ unsigned short f2bf(float f) {
    union { float f; unsigned int u; } c; c.f = f;
    unsigned int r = c.u + 0x7FFF + ((c.u >> 16) & 1);   // RNE (precompute path)
    return (unsigned short)(r >> 16);
}
// fast pack: round-half-away (0.5 ulp, same bound as RNE): 2 add + 1 perm
static __device__ __forceinline__ unsigned int pk2rn(float lo, float hi) {
    union { float f; unsigned int u; } a, b;
    a.f = lo; b.f = hi;
    return __builtin_amdgcn_perm(b.u + 0x8000u, a.u + 0x8000u, 0x07060302u);
}
static __device__ __forceinline__ float u2f_lo(unsigned int u) {
    union { float f; unsigned int i; } c; c.i = u << 16; return c.f;
}
static __device__ __forceinline__ float u2f_hi(unsigned int u) {
    union { float f; unsigned int i; } c; c.i = u & 0xffff0000u; return c.f;
}

// ---------------------------------------------------------------------------
// Kernel P: Wcomb[z][64][256] = W_exp @ W_{l,r}[2] (f32)
//           cadd[z][100][256] = (b_exp + pe[n]) @ W_{l,r}[2] + b_{l,r}[2] (f32)
// ---------------------------------------------------------------------------
__global__ __launch_bounds__(256) void precompute_k(
    const float* __restrict__ W_exp, const float* __restrict__ b_exp,
    const float* __restrict__ W_l, const float* __restrict__ b_l,
    const float* __restrict__ W_r, const float* __restrict__ b_r,
    float* __restrict__ Wcomb, float* __restrict__ cadd)
{
    int r = blockIdx.x;           // 0..163
    int z = blockIdx.y;           // 0 = l, 1 = r
    int t = threadIdx.x;          // output col
    const float* Wg = (z ? W_r : W_l) + 2 * HH * HH;  // layer 2
    const float* bg = (z ? b_r : b_l) + 2 * HH;

    __shared__ float sa[HH];
    float a;
    if (r < INF_) {
        a = W_exp[r * HH + t];
    } else {
        int n = r - INF_;
        float div = expf((float)(t & 254) * (-0.03597789207803f));
        float ang = (float)n * div;
        a = b_exp[t] + ((t & 1) ? cosf(ang) : sinf(ang));
    }
    sa[t] = a;
    __syncthreads();

    float acc = 0.f;
    #pragma unroll 8
    for (int h = 0; h < HH; ++h)
        acc += sa[h] * Wg[h * HH + t];

    if (r < INF_) Wcomb[(z * INF_ + r) * HH + t] = acc;
    else          cadd[(z * NN + (r - INF_)) * HH + t] = acc + bg[t];
}

// ---------------------------------------------------------------------------
// Kernel R: rearrange into MFMA fragment layouts.
//  WF (bf16) [z][nt:16][ks:2][lane:64][j:8] : Wcomb[z][k][n],
//      k = ks*32 + 4*(lane>>4) + (j&3) + 16*(j>>2),  n = nt*16 + (lane&15)
//  CFf (f32) [z][mt:7][nt:16][lane:64][r:4] : cadd[z][node][feat],
//      node = mt*16 + (lane&15), feat = nt*16 + (lane>>4)*4 + r  (node>=100 -> 0)
//  (CFf matches the SWAPPED-operand D layout: D[feat][node], col=lane&15=node)
// ---------------------------------------------------------------------------
#define N_WF 32768
#define N_CF4 14336   // float4 slots

__global__ __launch_bounds__(256) void rearrange_k(
    const float* __restrict__ Wcomb, const float* __restrict__ cadd,
    unsigned short* __restrict__ WF, float* __restrict__ CFf)
{
    int i = blockIdx.x * 256 + threadIdx.x;
    if (i < N_WF) {
        int j = i & 7, lane = (i >> 3) & 63, ks = (i >> 9) & 1;
        int nt = (i >> 10) & 15, z = (i >> 14) & 1;
        int k = ks * 32 + 4 * (lane >> 4) + (j & 3) + 16 * (j >> 2);
        int n = nt * 16 + (lane & 15);
        WF[i] = f2bf(Wcomb[(z * INF_ + k) * HH + n]);
    } else if (i < N_WF + N_CF4) {
        int i2 = i - N_WF;
        int lane = i2 & 63, nt = (i2 >> 6) & 15;
        int zm = i2 >> 10;                 // 0..13
        int mt = zm % 7, z = zm / 7;
        int node = mt * 16 + (lane & 15);
        int feat = nt * 16 + (lane >> 4) * 4;
        float4 v = {0.f, 0.f, 0.f, 0.f};
        if (node < NN)
            v = *(const float4*)&cadd[(z * NN + node) * HH + feat];
        *(float4*)&CFf[(size_t)i2 * 4] = v;
    }
}

// ---------------------------------------------------------------------------
// Kernel F (fused): one block per batch, 512 threads (8 waves), 3 blocks/CU.
//  Stage x[b] -> LDS bf16 fragments (sxs). Quarter loop (64 cols): swapped
//  MFMA (D[feat][node], CFf C-init) -> perm-pack bf16 -> padded quarter-local
//  sxl/sxr ([100][72], bank-conflict-free via pad); balanced edge-logit
//  accumulation. Tail: 8-lane shfl reduce -> lg, softmax -> wv, pooled
//  computed ALGEBRAICALLY: pooled = (wv@x)@Wcomb_l + wv@cadd_l (f32), FC.
//  LDS = 14400+14400+14336+1024 = 44160 B -> 3 blocks/CU, VGPR cap ~84.
// ---------------------------------------------------------------------------
__global__ __launch_bounds__(512, 6) void fused_k(
    const float* __restrict__ x,
    const unsigned short* __restrict__ WF, const float* __restrict__ CFf,
    const float* __restrict__ Wcomb, const float* __restrict__ cadd,
    const float* __restrict__ att, const float* __restrict__ bias,
    const float* __restrict__ Wfc, const float* __restrict__ bfc,
    float* __restrict__ out)
{
    __shared__ unsigned short sxl[NN * QP];    // 14400 B quarter xl (padded)
    __shared__ unsigned short sxr[NN * QP];    // 14400 B quarter xr (padded)
    __shared__ unsigned short sxs[896 * 8];    // 14336 B x-frags; later lg/wv/ypart
    __shared__ float satt[HH];                 // 1024 B

    int b = blockIdx.x, t = threadIdx.x;
    int wave = t >> 6, lane = t & 63, g = lane >> 4, li = lane & 15;

    if (t < HH) satt[t] = att[2 * HH + t];

    // ---- stage x[b] as bf16 fragments (B-operand for swapped mfma) ----
    const float* xb = x + (size_t)b * (NN * INF_);
    for (int s = t; s < 896; s += 512) {
        int sl = s & 63, ks = (s >> 6) & 1, mt = s >> 7;
        int m = mt * 16 + (sl & 15), gg = sl >> 4;
        union { s8v v; unsigned int u[4]; } a;
        if (m < NN) {
            float4 u = *(const float4*)&xb[m * INF_ + ks * 32 + 4 * gg];
            float4 v = *(const float4*)&xb[m * INF_ + ks * 32 + 16 + 4 * gg];
            a.u[0] = pk2rn(u.x, u.y);
            a.u[1] = pk2rn(u.z, u.w);
            a.u[2] = pk2rn(v.x, v.y);
            a.u[3] = pk2rn(v.z, v.w);
        } else {
            a.u[0] = a.u[1] = a.u[2] = a.u[3] = 0u;
        }
        *(s8v*)&sxs[s * 8] = a.v;
    }

    // ---- per-thread edge slots: edges e = (t>>3)+64i, col chunk c8 = (t&7)*8 ----
    int q8 = t >> 3, c8 = (t & 7) * 8;
    int eBL[5], eBR[5];
    bool eva[5];
    float pv[5], pa[5];
    #pragma unroll
    for (int i = 0; i < 5; ++i) {
        int e = q8 + 64 * i;
        bool inr = (e < 300);
        int es = inr ? (e / 3) : 0;
        int ed = es + (e - 3 * es) - 1;          // dst
        bool v = inr && ed >= 0 && ed < NN;
        eva[i] = v;
        int dd = v ? ed : 0;
        eBL[i] = 2 * (es * QP + c8);             // byte, quarter-local (padded)
        eBR[i] = 2 * (dd * QP + c8);
        pv[i] = 0.f; pa[i] = 0.f;
    }

    int z = wave >> 2;          // waves 0-3: xl, 4-7: xr
    int ntw = wave & 3;
    __syncthreads();

    #pragma unroll
    for (int q = 0; q < 4; ++q) {
        // ---- MFMA quarter: wave owns tile (z, nt) ----
        int nt = q * 4 + ntw;
        const s8v* bp = (const s8v*)WF + (size_t)(z * 16 + nt) * 2 * 64;
        s8v w0 = bp[lane];            // ks=0 (A-operand: W^T)
        s8v w1 = bp[64 + lane];       // ks=1
        const s8v* sp = (const s8v*)sxs;
        unsigned short* dstp = z ? sxr : sxl;
        int colbase = ntw * 16 + g * 4;
        #pragma unroll
        for (int mt = 0; mt < 7; ++mt) {
            f4v c = *(const f4v*)&CFf[((size_t)((z * 7 + mt) * 16 + nt) * 64 + lane) * 4];
            s8v a0 = sp[mt * 128 + lane];
            s8v a1 = sp[mt * 128 + 64 + lane];
            c = __builtin_amdgcn_mfma_f32_16x16x32_bf16(w0, a0, c, 0, 0, 0);
            c = __builtin_amdgcn_mfma_f32_16x16x32_bf16(w1, a1, c, 0, 0, 0);
            int node = mt * 16 + li;
            if (mt < 6 || li < 4) {              // node < 100
                unsigned int lo = pk2rn(c[0], c[1]);
                unsigned int hi = pk2rn(c[2], c[3]);
                int elem = node * QP + colbase;
                uint2 wv2 = { lo, hi };
                *(uint2*)&dstp[elem] = wv2;      // ds_write_b64, 4 features
            }
        }
        __syncthreads();

        // ---- balanced logits over this quarter's 64 cols ----
        float4 at0 = *(const float4*)&satt[q * 64 + c8];
        float4 at1 = *(const float4*)&satt[q * 64 + c8 + 4];
        #pragma unroll
        for (int i = 0; i < 5; ++i) {
            if (eva[i]) {
                uint4 ua = *(const uint4*)((const char*)sxl + eBL[i]);
                uint4 ub = *(const uint4*)((const char*)sxr + eBR[i]);
                float fv, fa;
                #define PROC(UL, UR, A0, A1) { \
                    float v0 = u2f_lo(UL) + u2f_lo(UR); \
                    float v1 = u2f_hi(UL) + u2f_hi(UR); \
                    fv = fmaf(A0, v0, fv); fa = fmaf(A0, fabsf(v0), fa); \
                    fv = fmaf(A1, v1, fv); fa = fmaf(A1, fabsf(v1), fa); }
                fv = 0.f; fa = 0.f;
                PROC(ua.x, ub.x, at0.x, at0.y);
                PROC(ua.y, ub.y, at0.z, at0.w);
                PROC(ua.z, ub.z, at1.x, at1.y);
                PROC(ua.w, ub.w, at1.z, at1.w);
                #undef PROC
                pv[i] += fv; pa[i] += fa;
            }
        }
        __syncthreads();
    }

    // sxs frags are dead; carve scratch from it (all 16B-aligned offsets)
    float* lg      = (float*)sxs;          // 300 floats
    float* wvp     = lg + 304;             // 100 floats
    float* partial = wvp + 104;            // 12 floats
    float* ypart   = partial + 16;         // 8*64 floats

    // ---- reduce slot partials across 8-lane groups -> lg ----
    #pragma unroll
    for (int i = 0; i < 5; ++i) {
        // leaky(v) = 0.6v + 0.4|v|, factored: lg = 0.6*pv + 0.4*pa
        float s = fmaf(0.6f, pv[i], 0.4f * pa[i]);
        s += __shfl_xor(s, 1, 64);
        s += __shfl_xor(s, 2, 64);
        s += __shfl_xor(s, 4, 64);
        int e = q8 + 64 * i;
        if ((t & 7) == 0 && e < 300)
            lg[e] = eva[i] ? s : -1e30f;
    }
    __syncthreads();

    // ---- wv[i] = sum over dst j in {i-1,i,i+1} of alpha(i->j) ----
    if (t < NN) {
        int i = t;
        float w = 0.f;
        #pragma unroll
        for (int dj = -1; dj <= 1; ++dj) {
            int j = i + dj;
            if (j < 0 || j >= NN) continue;
            float l0 = (j - 1 >= 0) ? lg[3 * (j - 1) + 2] : -1e30f;  // j-1 -> j
            float l1 = lg[3 * j + 1];                                 // j   -> j
            float l2 = (j + 1 < NN) ? lg[3 * (j + 1) + 0] : -1e30f;  // j+1 -> j
            float mx = fmaxf(fmaxf(l0, l1), l2);
            float den = expf(l0 - mx) + expf(l1 - mx) + expf(l2 - mx);
            float myl = lg[3 * i + dj + 1];
            w += expf(myl - mx) / den;
        }
        wvp[i] = w;
    }
    __syncthreads();

    // ---- y[k] = sum_i wv[i] * x[b][i][k]  (k < 64), per-wave row chunks ----
    {
        int r0 = wave * 13;
        int r1 = (r0 + 13 < NN) ? r0 + 13 : NN;
        float acc = 0.f;
        for (int i = r0; i < r1; ++i)
            acc = fmaf(wvp[i], xb[i * INF_ + lane], acc);
        ypart[wave * 64 + lane] = acc;
    }
    __syncthreads();
    if (t < 64) {
        float s = 0.f;
        #pragma unroll
        for (int w = 0; w < 8; ++w) s += ypart[w * 64 + t];
        ypart[t] = s;                       // y[k]
    }
    __syncthreads();

    // ---- pooled[f] = y @ Wcomb_l[:,f] + wv @ cadd_l[:,f] + 100*bias[f]; FC ----
    if (t < HH) {
        float p = 100.f * bias[2 * HH + t];
        #pragma unroll
        for (int k = 0; k < INF_; k += 4) {
            float4 y4 = *(const float4*)&ypart[k];
            p = fmaf(y4.x, Wcomb[(k + 0) * HH + t], p);
            p = fmaf(y4.y, Wcomb[(k + 1) * HH + t], p);
            p = fmaf(y4.z, Wcomb[(k + 2) * HH + t], p);
            p = fmaf(y4.w, Wcomb[(k + 3) * HH + t], p);
        }
        #pragma unroll
        for (int i = 0; i < NN; i += 4) {
            float4 w4 = *(const float4*)&wvp[i];
            p = fmaf(w4.x, cadd[(i + 0) * HH + t], p);
            p = fmaf(w4.y, cadd[(i + 1) * HH + t], p);
            p = fmaf(w4.z, cadd[(i + 2) * HH + t], p);
            p = fmaf(w4.w, cadd[(i + 3) * HH + t], p);
        }

        float p0 = p * Wfc[t * 3 + 0];
        float p1 = p * Wfc[t * 3 + 1];
        float p2 = p * Wfc[t * 3 + 2];
        #pragma unroll
        for (int off = 32; off; off >>= 1) {
            p0 += __shfl_down(p0, off, 64);
            p1 += __shfl_down(p1, off, 64);
            p2 += __shfl_down(p2, off, 64);
        }
        if (lane == 0) {
            partial[wave * 3 + 0] = p0;
            partial[wave * 3 + 1] = p1;
            partial[wave * 3 + 2] = p2;
        }
    }
    __syncthreads();
    if (t < CC) {
        out[(size_t)b * CC + t] =
            partial[0 * 3 + t] + partial[1 * 3 + t] +
            partial[2 * 3 + t] + partial[3 * 3 + t] + bfc[t];
    }
}

// ---------------------------------------------------------------------------
extern "C" void kernel_launch(void* const* d_in, const int* in_sizes, int n_in,
                              void* d_out, int out_size, void* d_ws, size_t ws_size,
                              hipStream_t stream) {
    const float* x     = (const float*)d_in[0];
    const float* W_exp = (const float*)d_in[1];
    const float* b_exp = (const float*)d_in[2];
    const float* W_l   = (const float*)d_in[3];
    const float* b_l   = (const float*)d_in[4];
    const float* W_r   = (const float*)d_in[5];
    const float* b_r   = (const float*)d_in[6];
    const float* att   = (const float*)d_in[7];
    const float* bias  = (const float*)d_in[8];
    const float* W_fc  = (const float*)d_in[9];
    const float* b_fc  = (const float*)d_in[10];
    float* out = (float*)d_out;

    // workspace layout (16B aligned)
    char* ws = (char*)d_ws;
    float* Wcomb = (float*)ws;                                             // 131072 B
    float* cadd  = (float*)(ws + 131072);                                  // 204800 B
    unsigned short* WF = (unsigned short*)(ws + 131072 + 204800);          // 65536 B
    float* CFf = (float*)(ws + 131072 + 204800 + 65536);                   // 229376 B

    precompute_k<<<dim3(164, 2), 256, 0, stream>>>(W_exp, b_exp, W_l, b_l, W_r, b_r,
                                                   Wcomb, cadd);
    rearrange_k<<<184, 256, 0, stream>>>(Wcomb, cadd, WF, CFf);
    fused_k<<<BB, 512, 0, stream>>>(x, WF, CFf, Wcomb, cadd, att, bias, W_fc, b_fc, out);
}

// Round 11
// 81.410 us; speedup vs baseline: 1.1146x; 1.0396x over previous
//
#include <hip/hip_runtime.h>
#include <hip/hip_bf16.h>
#include <hip/hip_fp16.h>

// Problem constants
#define BB 2048
#define NN 100
#define INF_ 64
#define HH 256
#define CC 3
#define QP 72   // padded quarter-row stride (fp16 elems): 144B -> 4-bank rotate/row

typedef __attribute__((ext_vector_type(8))) _Float16 h8v;  // 8 fp16 (4 VGPRs)
typedef __attribute__((ext_vector_type(2))) _Float16 h2v;  // packed pair (_Float16)
typedef __attribute__((ext_vector_type(2))) __fp16   g2v;  // packed pair (__fp16, builtin ABI)
typedef __attribute__((ext_vector_type(4))) float f4v;     // 4 fp32 acc

// pack 2 f32 -> packed fp16 (RTZ, single v_cvt_pkrtz_f16_f32)
static __device__ __forceinline__ unsigned int pkh(float lo, float hi) {
    union { g2v g; unsigned int u; } c;
    c.g = __builtin_amdgcn_cvt_pkrtz(lo, hi);
    return c.u;
}

// ---------------------------------------------------------------------------
// Kernel P: Wcomb[z][64][256] = W_exp @ W_{l,r}[2] (f32)
//           cadd[z][100][256] = (b_exp + pe[n]) @ W_{l,r}[2] + b_{l,r}[2] (f32)
// ---------------------------------------------------------------------------
__global__ __launch_bounds__(256) void precompute_k(
    const float* __restrict__ W_exp, const float* __restrict__ b_exp,
    const float* __restrict__ W_l, const float* __restrict__ b_l,
    const float* __restrict__ W_r, const float* __restrict__ b_r,
    float* __restrict__ Wcomb, float* __restrict__ cadd)
{
    int r = blockIdx.x;           // 0..163
    int z = blockIdx.y;           // 0 = l, 1 = r
    int t = threadIdx.x;          // output col
    const float* Wg = (z ? W_r : W_l) + 2 * HH * HH;  // layer 2
    const float* bg = (z ? b_r : b_l) + 2 * HH;

    __shared__ float sa[HH];
    float a;
    if (r < INF_) {
        a = W_exp[r * HH + t];
    } else {
        int n = r - INF_;
        float div = expf((float)(t & 254) * (-0.03597789207803f));
        float ang = (float)n * div;
        a = b_exp[t] + ((t & 1) ? cosf(ang) : sinf(ang));
    }
    sa[t] = a;
    __syncthreads();

    float acc = 0.f;
    #pragma unroll 8
    for (int h = 0; h < HH; ++h)
        acc += sa[h] * Wg[h * HH + t];

    if (r < INF_) Wcomb[(z * INF_ + r) * HH + t] = acc;
    else          cadd[(z * NN + (r - INF_)) * HH + t] = acc + bg[t];
}

// ---------------------------------------------------------------------------
// Kernel R: rearrange into MFMA fragment layouts (fp16 weights, f32 C-init).
//  WF (fp16) [z][nt:16][ks:2][lane:64][j:8] : Wcomb[z][k][n],
//      k = ks*32 + 4*(lane>>4) + (j&3) + 16*(j>>2),  n = nt*16 + (lane&15)
//  CFf (f32) [z][mt:7][nt:16][lane:64][r:4] : cadd[z][node][feat],
//      node = mt*16 + (lane&15), feat = nt*16 + (lane>>4)*4 + r  (node>=100 -> 0)
//  (CFf matches the SWAPPED-operand D layout: D[feat][node], col=lane&15=node)
// ---------------------------------------------------------------------------
#define N_WF 32768
#define N_CF4 14336   // float4 slots

__global__ __launch_bounds__(256) void rearrange_k(
    const float* __restrict__ Wcomb, const float* __restrict__ cadd,
    unsigned short* __restrict__ WF, float* __restrict__ CFf)
{
    int i = blockIdx.x * 256 + threadIdx.x;
    if (i < N_WF) {
        int j = i & 7, lane = (i >> 3) & 63, ks = (i >> 9) & 1;
        int nt = (i >> 10) & 15, z = (i >> 14) & 1;
        int k = ks * 32 + 4 * (lane >> 4) + (j & 3) + 16 * (j >> 2);
        int n = nt * 16 + (lane & 15);
        __half h = __float2half(Wcomb[(z * INF_ + k) * HH + n]);   // RNE
        WF[i] = __half_as_ushort(h);
    } else if (i < N_WF + N_CF4) {
        int i2 = i - N_WF;
        int lane = i2 & 63, nt = (i2 >> 6) & 15;
        int zm = i2 >> 10;                 // 0..13
        int mt = zm % 7, z = zm / 7;
        int node = mt * 16 + (lane & 15);
        int feat = nt * 16 + (lane >> 4) * 4;
        float4 v = {0.f, 0.f, 0.f, 0.f};
        if (node < NN)
            v = *(const float4*)&cadd[(z * NN + node) * HH + feat];
        *(float4*)&CFf[(size_t)i2 * 4] = v;
    }
}

// ---------------------------------------------------------------------------
// Kernel F (fused): one block per batch, 512 threads (8 waves), 3 blocks/CU.
//  Stage x[b] -> LDS fp16 fragments (sxs). Quarter loop (64 cols): swapped
//  f16 MFMA (D[feat][node], CFf C-init) -> cvt_pkrtz -> padded quarter-local
//  sxl/sxr ([100][72]); balanced edge-logit accumulation with PACKED fp16
//  math (v_pk_add_f16 + v_dot2_f32_f16). Tail: 8-lane shfl reduce -> lg,
//  softmax -> wv, pooled ALGEBRAIC: (wv@x)@Wcomb_l + wv@cadd_l (f32), FC.
//  LDS = 14400+14400+14336+512 = 43648 B -> 3 blocks/CU.
// ---------------------------------------------------------------------------
__global__ __launch_bounds__(512, 6) void fused_k(
    const float* __restrict__ x,
    const unsigned short* __restrict__ WF, const float* __restrict__ CFf,
    const float* __restrict__ Wcomb, const float* __restrict__ cadd,
    const float* __restrict__ att, const float* __restrict__ bias,
    const float* __restrict__ Wfc, const float* __restrict__ bfc,
    float* __restrict__ out)
{
    __shared__ unsigned short sxl[NN * QP];    // 14400 B quarter xl (padded)
    __shared__ unsigned short sxr[NN * QP];    // 14400 B quarter xr (padded)
    __shared__ unsigned short sxs[896 * 8];    // 14336 B x-frags; later lg/wv/ypart
    __shared__ unsigned int satt2[HH / 2];     // 512 B packed att (fp16 pairs)

    int b = blockIdx.x, t = threadIdx.x;
    int wave = t >> 6, lane = t & 63, g = lane >> 4, li = lane & 15;

    if (t < HH / 2) satt2[t] = pkh(att[2 * HH + 2 * t], att[2 * HH + 2 * t + 1]);

    // ---- stage x[b] as fp16 fragments (B-operand for swapped mfma) ----
    const float* xb = x + (size_t)b * (NN * INF_);
    for (int s = t; s < 896; s += 512) {
        int sl = s & 63, ks = (s >> 6) & 1, mt = s >> 7;
        int m = mt * 16 + (sl & 15), gg = sl >> 4;
        union { h8v v; unsigned int u[4]; } a;
        if (m < NN) {
            float4 u = *(const float4*)&xb[m * INF_ + ks * 32 + 4 * gg];
            float4 v = *(const float4*)&xb[m * INF_ + ks * 32 + 16 + 4 * gg];
            a.u[0] = pkh(u.x, u.y);
            a.u[1] = pkh(u.z, u.w);
            a.u[2] = pkh(v.x, v.y);
            a.u[3] = pkh(v.z, v.w);
        } else {
            a.u[0] = a.u[1] = a.u[2] = a.u[3] = 0u;
        }
        *(h8v*)&sxs[s * 8] = a.v;
    }

    // ---- per-thread edge slots: edges e = (t>>3)+64i, col chunk c8 = (t&7)*8 ----
    int q8 = t >> 3, c8 = (t & 7) * 8;
    int eBL[5], eBR[5];
    bool eva[5];
    float pv[5], pa[5];
    #pragma unroll
    for (int i = 0; i < 5; ++i) {
        int e = q8 + 64 * i;
        bool inr = (e < 300);
        int es = inr ? (e / 3) : 0;
        int ed = es + (e - 3 * es) - 1;          // dst
        bool v = inr && ed >= 0 && ed < NN;
        eva[i] = v;
        int dd = v ? ed : 0;
        eBL[i] = 2 * (es * QP + c8);             // byte, quarter-local (padded)
        eBR[i] = 2 * (dd * QP + c8);
        pv[i] = 0.f; pa[i] = 0.f;
    }

    int z = wave >> 2;          // waves 0-3: xl, 4-7: xr
    int ntw = wave & 3;
    __syncthreads();

    #pragma unroll
    for (int q = 0; q < 4; ++q) {
        // ---- MFMA quarter: wave owns tile (z, nt) ----
        int nt = q * 4 + ntw;
        const h8v* bp = (const h8v*)WF + (size_t)(z * 16 + nt) * 2 * 64;
        h8v w0 = bp[lane];            // ks=0 (A-operand: W^T)
        h8v w1 = bp[64 + lane];       // ks=1
        const h8v* sp = (const h8v*)sxs;
        unsigned short* dstp = z ? sxr : sxl;
        int colbase = ntw * 16 + g * 4;
        #pragma unroll
        for (int mt = 0; mt < 7; ++mt) {
            f4v c = *(const f4v*)&CFf[((size_t)((z * 7 + mt) * 16 + nt) * 64 + lane) * 4];
            h8v a0 = sp[mt * 128 + lane];
            h8v a1 = sp[mt * 128 + 64 + lane];
            c = __builtin_amdgcn_mfma_f32_16x16x32_f16(w0, a0, c, 0, 0, 0);
            c = __builtin_amdgcn_mfma_f32_16x16x32_f16(w1, a1, c, 0, 0, 0);
            int node = mt * 16 + li;
            if (mt < 6 || li < 4) {              // node < 100
                unsigned int lo = pkh(c[0], c[1]);
                unsigned int hi = pkh(c[2], c[3]);
                int elem = node * QP + colbase;
                uint2 wv2 = { lo, hi };
                *(uint2*)&dstp[elem] = wv2;      // ds_write_b64, 4 features
            }
        }
        __syncthreads();

        // ---- balanced logits over this quarter's 64 cols (packed fp16) ----
        uint4 atv = *(const uint4*)&satt2[q * 32 + (t & 7) * 4];
        #pragma unroll
        for (int i = 0; i < 5; ++i) {
            if (eva[i]) {
                uint4 ua = *(const uint4*)((const char*)sxl + eBL[i]);
                uint4 ub = *(const uint4*)((const char*)sxr + eBR[i]);
                float fv = 0.f, fa = 0.f;
                #define PROC(UA, UB, AT) { \
                    union UU { unsigned int u; h2v h; g2v g; }; \
                    UU xa, xb2, vv, va, at; \
                    xa.u = (UA); xb2.u = (UB); at.u = (AT); \
                    vv.h = xa.h + xb2.h;              /* v_pk_add_f16 */ \
                    va.u = vv.u & 0x7FFF7FFFu;        /* packed |v| */ \
                    fv = __builtin_amdgcn_fdot2(at.g, vv.g, fv, false); \
                    fa = __builtin_amdgcn_fdot2(at.g, va.g, fa, false); }
                PROC(ua.x, ub.x, atv.x);
                PROC(ua.y, ub.y, atv.y);
                PROC(ua.z, ub.z, atv.z);
                PROC(ua.w, ub.w, atv.w);
                #undef PROC
                pv[i] += fv; pa[i] += fa;
            }
        }
        __syncthreads();
    }

    // sxs frags are dead; carve scratch from it (all 16B-aligned offsets)
    float* lg      = (float*)sxs;          // 300 floats
    float* wvp     = lg + 304;             // 100 floats
    float* partial = wvp + 104;            // 12 floats
    float* ypart   = partial + 16;         // 8*64 floats

    // ---- reduce slot partials across 8-lane groups -> lg ----
    #pragma unroll
    for (int i = 0; i < 5; ++i) {
        // leaky(v) = 0.6v + 0.4|v|, factored: lg = 0.6*pv + 0.4*pa
        float s = fmaf(0.6f, pv[i], 0.4f * pa[i]);
        s += __shfl_xor(s, 1, 64);
        s += __shfl_xor(s, 2, 64);
        s += __shfl_xor(s, 4, 64);
        int e = q8 + 64 * i;
        if ((t & 7) == 0 && e < 300)
            lg[e] = eva[i] ? s : -1e30f;
    }
    __syncthreads();

    // ---- wv[i] = sum over dst j in {i-1,i,i+1} of alpha(i->j) ----
    if (t < NN) {
        int i = t;
        float w = 0.f;
        #pragma unroll
        for (int dj = -1; dj <= 1; ++dj) {
            int j = i + dj;
            if (j < 0 || j >= NN) continue;
            float l0 = (j - 1 >= 0) ? lg[3 * (j - 1) + 2] : -1e30f;  // j-1 -> j
            float l1 = lg[3 * j + 1];                                 // j   -> j
            float l2 = (j + 1 < NN) ? lg[3 * (j + 1) + 0] : -1e30f;  // j+1 -> j
            float mx = fmaxf(fmaxf(l0, l1), l2);
            float den = expf(l0 - mx) + expf(l1 - mx) + expf(l2 - mx);
            float myl = lg[3 * i + dj + 1];
            w += expf(myl - mx) / den;
        }
        wvp[i] = w;
    }
    __syncthreads();

    // ---- y[k] = sum_i wv[i] * x[b][i][k]  (k < 64), per-wave row chunks ----
    {
        int r0 = wave * 13;
        int r1 = (r0 + 13 < NN) ? r0 + 13 : NN;
        float acc = 0.f;
        for (int i = r0; i < r1; ++i)
            acc = fmaf(wvp[i], xb[i * INF_ + lane], acc);
        ypart[wave * 64 + lane] = acc;
    }
    __syncthreads();
    if (t < 64) {
        float s = 0.f;
        #pragma unroll
        for (int w = 0; w < 8; ++w) s += ypart[w * 64 + t];
        ypart[t] = s;                       // y[k]
    }
    __syncthreads();

    // ---- pooled[f] = y @ Wcomb_l[:,f] + wv @ cadd_l[:,f] + 100*bias[f]; FC ----
    if (t < HH) {
        float p = 100.f * bias[2 * HH + t];
        #pragma unroll
        for (int k = 0; k < INF_; k += 4) {
            float4 y4 = *(const float4*)&ypart[k];
            p = fmaf(y4.x, Wcomb[(k + 0) * HH + t], p);
            p = fmaf(y4.y, Wcomb[(k + 1) * HH + t], p);
            p = fmaf(y4.z, Wcomb[(k + 2) * HH + t], p);
            p = fmaf(y4.w, Wcomb[(k + 3) * HH + t], p);
        }
        #pragma unroll
        for (int i = 0; i < NN; i += 4) {
            float4 w4 = *(const float4*)&wvp[i];
            p = fmaf(w4.x, cadd[(i + 0) * HH + t], p);
            p = fmaf(w4.y, cadd[(i + 1) * HH + t], p);
            p = fmaf(w4.z, cadd[(i + 2) * HH + t], p);
            p = fmaf(w4.w, cadd[(i + 3) * HH + t], p);
        }

        float p0 = p * Wfc[t * 3 + 0];
        float p1 = p * Wfc[t * 3 + 1];
        float p2 = p * Wfc[t * 3 + 2];
        #pragma unroll
        for (int off = 32; off; off >>= 1) {
            p0 += __shfl_down(p0, off, 64);
            p1 += __shfl_down(p1, off, 64);
            p2 += __shfl_down(p2, off, 64);
        }
        if (lane == 0) {
            partial[wave * 3 + 0] = p0;
            partial[wave * 3 + 1] = p1;
            partial[wave * 3 + 2] = p2;
        }
    }
    __syncthreads();
    if (t < CC) {
        out[(size_t)b * CC + t] =
            partial[0 * 3 + t] + partial[1 * 3 + t] +
            partial[2 * 3 + t] + partial[3 * 3 + t] + bfc[t];
    }
}

// ---------------------------------------------------------------------------
extern "C" void kernel_launch(void* const* d_in, const int* in_sizes, int n_in,
                              void* d_out, int out_size, void* d_ws, size_t ws_size,
                              hipStream_t stream) {
    const float* x     = (const float*)d_in[0];
    const float* W_exp = (const float*)d_in[1];
    const float* b_exp = (const float*)d_in[2];
    const float* W_l   = (const float*)d_in[3];
    const float* b_l   = (const float*)d_in[4];
    const float* W_r   = (const float*)d_in[5];
    const float* b_r   = (const float*)d_in[6];
    const float* att   = (const float*)d_in[7];
    const float* bias  = (const float*)d_in[8];
    const float* W_fc  = (const float*)d_in[9];
    const float* b_fc  = (const float*)d_in[10];
    float* out = (float*)d_out;

    // workspace layout (16B aligned)
    char* ws = (char*)d_ws;
    float* Wcomb = (float*)ws;                                             // 131072 B
    float* cadd  = (float*)(ws + 131072);                                  // 204800 B
    unsigned short* WF = (unsigned short*)(ws + 131072 + 204800);          // 65536 B
    float* CFf = (float*)(ws + 131072 + 204800 + 65536);                   // 229376 B

    precompute_k<<<dim3(164, 2), 256, 0, stream>>>(W_exp, b_exp, W_l, b_l, W_r, b_r,
                                                   Wcomb, cadd);
    rearrange_k<<<184, 256, 0, stream>>>(Wcomb, cadd, WF, CFf);
    fused_k<<<BB, 512, 0, stream>>>(x, WF, CFf, Wcomb, cadd, att, bias, W_fc, b_fc, out);
}